// Round 2
// baseline (1311.013 us; speedup 1.0000x reference)
//
#include <hip/hip_runtime.h>
#include <math.h>

#define N_NODES 50000
#define N_EDGES 800000
#define R_REL 8
#define H_DIM 128
#define C_OUT 64

typedef __attribute__((ext_vector_type(8))) __bf16 bf16x8;
typedef __attribute__((ext_vector_type(4))) float f32x4;

// ---------------- CSR build (dst-sorted edge list) ----------------

__global__ void k_hist(const int* __restrict__ dst, int* __restrict__ hist) {
  int e = blockIdx.x * blockDim.x + threadIdx.x;
  if (e < N_EDGES) atomicAdd(&hist[dst[e]], 1);
}

__global__ void k_scan(const int* __restrict__ hist, int* __restrict__ rowptr,
                       int* __restrict__ cursor) {
  __shared__ int tmp[1024];
  int tid = threadIdx.x;
  int carry = 0;
  for (int base = 0; base < N_NODES; base += 1024) {
    int idx = base + tid;
    int v = (idx < N_NODES) ? hist[idx] : 0;
    tmp[tid] = v;
    __syncthreads();
    for (int off = 1; off < 1024; off <<= 1) {
      int t = (tid >= off) ? tmp[tid - off] : 0;
      __syncthreads();
      tmp[tid] += t;
      __syncthreads();
    }
    int excl = carry + tmp[tid] - v;
    if (idx < N_NODES) { rowptr[idx] = excl; cursor[idx] = excl; }
    carry += tmp[1023];
    __syncthreads();
  }
  if (tid == 0) rowptr[N_NODES] = carry;
}

__global__ void k_scatter(const int* __restrict__ src, const int* __restrict__ dst,
                          const int* __restrict__ et, int* __restrict__ cursor,
                          int* __restrict__ ssrc, int* __restrict__ setype) {
  int e = blockIdx.x * blockDim.x + threadIdx.x;
  if (e < N_EDGES) {
    int d = dst[e];
    int p = atomicAdd(&cursor[d], 1);
    ssrc[p] = src[e];
    setype[p] = et[e];
  }
}

// ---------------- W prep: transpose + split-bf16 convert ----------------
// Wt[l][r][o][f] (hi/lo bf16) from W_l[r][f][o] fp32. 3*8*128*128 elements.

__global__ void k_prepw(const float* __restrict__ W1, const float* __restrict__ W2,
                        const float* __restrict__ W3,
                        __bf16* __restrict__ Whi, __bf16* __restrict__ Wlo) {
  int idx = blockIdx.x * blockDim.x + threadIdx.x;  // [l][r][o][f]
  if (idx >= 3 * R_REL * 128 * 128) return;
  int f = idx & 127;
  int o = (idx >> 7) & 127;
  int r = (idx >> 14) & 7;
  int l = idx >> 17;
  const float* W = (l == 0) ? W1 : (l == 1) ? W2 : W3;
  float v = W[(r << 14) + (f << 7) + o];
  __bf16 h = (__bf16)v;
  Whi[idx] = h;
  Wlo[idx] = (__bf16)(v - (float)h);
}

// ---------------- MFMA transform: xr[n,r,:] = X[n,:] @ W[r], + qx/kx ----------------
// grid = ceil(N/64), block 256 (4 waves, 16 nodes each). Split-bf16, 3 MFMAs per
// (hi*hi + hi*lo + lo*hi), 16x16x32. A (X) loaded once, reused for all 8 relations.

__global__ __launch_bounds__(256) void k_transform_mfma(
    const float* __restrict__ X,
    const __bf16* __restrict__ Whi, const __bf16* __restrict__ Wlo,
    const float* __restrict__ qv, const float* __restrict__ kv,
    float* __restrict__ xr, float* __restrict__ qx, float* __restrict__ kx)
{
  const int tid  = threadIdx.x;
  const int wave = tid >> 6;
  const int lane = tid & 63;
  const int quad = lane >> 4;      // 0..3
  const int c    = lane & 15;      // col-within-tile / A-row node
  const int n0   = blockIdx.x * 64 + wave * 16;

  // ---- load X rows (A fragments), convert to split bf16 ----
  const int anode = n0 + c;
  const int aclamp = (anode < N_NODES) ? anode : (N_NODES - 1);
  const float4* Xv = (const float4*)(X + (size_t)aclamp * 128);
  bf16x8 Ahi[4], Alo[4];
#pragma unroll
  for (int kb = 0; kb < 4; ++kb) {
    float4 a = Xv[kb * 8 + quad * 2];
    float4 b = Xv[kb * 8 + quad * 2 + 1];
    float xf[8] = {a.x, a.y, a.z, a.w, b.x, b.y, b.z, b.w};
#pragma unroll
    for (int j = 0; j < 8; ++j) {
      __bf16 h = (__bf16)xf[j];
      Ahi[kb][j] = h;
      Alo[kb][j] = (__bf16)(xf[j] - (float)h);
    }
  }

  // q/k vector entries for this lane's columns
  float qreg[8], kreg[8];
#pragma unroll
  for (int nt = 0; nt < 8; ++nt) {
    qreg[nt] = qv[nt * 16 + c];
    kreg[nt] = kv[nt * 16 + c];
  }

  for (int r = 0; r < R_REL; ++r) {
    f32x4 acc[8];
#pragma unroll
    for (int nt = 0; nt < 8; ++nt) acc[nt] = (f32x4){0.f, 0.f, 0.f, 0.f};

#pragma unroll
    for (int kb = 0; kb < 4; ++kb) {
#pragma unroll
      for (int nt = 0; nt < 8; ++nt) {
        size_t wb = ((size_t)(r * 128 + nt * 16 + c) << 7) + kb * 32 + quad * 8;
        bf16x8 bhi = *(const bf16x8*)(Whi + wb);
        bf16x8 blo = *(const bf16x8*)(Wlo + wb);
        acc[nt] = __builtin_amdgcn_mfma_f32_16x16x32_bf16(Ahi[kb], bhi, acc[nt], 0, 0, 0);
        acc[nt] = __builtin_amdgcn_mfma_f32_16x16x32_bf16(Ahi[kb], blo, acc[nt], 0, 0, 0);
        acc[nt] = __builtin_amdgcn_mfma_f32_16x16x32_bf16(Alo[kb], bhi, acc[nt], 0, 0, 0);
      }
    }

    // ---- store xr: D row = n0 + quad*4 + reg, col = nt*16 + c ----
#pragma unroll
    for (int reg = 0; reg < 4; ++reg) {
      int nr = n0 + quad * 4 + reg;
      if (nr < N_NODES) {
        float* dp = xr + (((size_t)nr * R_REL + r) << 7);
#pragma unroll
        for (int nt = 0; nt < 8; ++nt) dp[nt * 16 + c] = acc[nt][reg];
      }
    }

    // ---- qx/kx: per-node dot with q/k, reduce across the 16 col-lanes ----
    float pq[4], pk[4];
#pragma unroll
    for (int reg = 0; reg < 4; ++reg) {
      float sq = 0.f, sk = 0.f;
#pragma unroll
      for (int nt = 0; nt < 8; ++nt) {
        sq += acc[nt][reg] * qreg[nt];
        sk += acc[nt][reg] * kreg[nt];
      }
      pq[reg] = sq; pk[reg] = sk;
    }
#pragma unroll
    for (int off = 1; off < 16; off <<= 1) {
#pragma unroll
      for (int reg = 0; reg < 4; ++reg) {
        pq[reg] += __shfl_xor(pq[reg], off);
        pk[reg] += __shfl_xor(pk[reg], off);
      }
    }
    if (c == 0) {
#pragma unroll
      for (int reg = 0; reg < 4; ++reg) {
        int nr = n0 + quad * 4 + reg;
        if (nr < N_NODES) {
          qx[nr * R_REL + r] = pq[reg];
          kx[nr * R_REL + r] = pk[reg];
        }
      }
    }
  }
}

// ---------------- per-dst-node online-softmax aggregation ----------------

__global__ __launch_bounds__(64) void k_agg(
    const float* __restrict__ xr, const float* __restrict__ qx, const float* __restrict__ kx,
    const int* __restrict__ rowptr, const int* __restrict__ ssrc, const int* __restrict__ setype,
    const float* __restrict__ bias, float* __restrict__ out)
{
  const int nd = blockIdx.x;
  const int lane = threadIdx.x;
  const int s = rowptr[nd];
  const int deg = rowptr[nd + 1] - s;

  float m = -INFINITY, sum = 0.f, ax = 0.f, ay = 0.f;
  const float2* xr2 = (const float2*)xr;

  for (int c = 0; c < deg; c += 64) {
    int idx = c + lane;
    bool valid = idx < deg;
    int sn = 0, et = 0;
    float a = -INFINITY;
    if (valid) {
      sn = ssrc[s + idx];
      et = setype[s + idx];
      a = qx[nd * R_REL + et] + kx[sn * R_REL + et];
      a = (a >= 0.f) ? a : 0.2f * a;   // leaky relu, slope 0.2
    }
    float cm = a;
#pragma unroll
    for (int off = 32; off > 0; off >>= 1) cm = fmaxf(cm, __shfl_xor(cm, off));
    float mnew = fmaxf(m, cm);
    float scale = (m == -INFINITY) ? 0.f : __expf(m - mnew);
    sum *= scale; ax *= scale; ay *= scale;
    m = mnew;
    float e = valid ? __expf(a - m) : 0.f;
    float cs = e;
#pragma unroll
    for (int off = 32; off > 0; off >>= 1) cs += __shfl_xor(cs, off);
    sum += cs;
    int cnt = (deg - c < 64) ? (deg - c) : 64;
    for (int j = 0; j < cnt; ++j) {
      float w = __shfl(e, j);
      int sj = __shfl(sn, j);
      int ej = __shfl(et, j);
      float2 v = xr2[((size_t)sj * R_REL + ej) * 64 + lane];
      ax += w * v.x;
      ay += w * v.y;
    }
  }
  float inv = (deg > 0) ? 1.f / sum : 0.f;
  float2 bb = ((const float2*)bias)[lane];
  float ox = fmaxf(ax * inv + bb.x, 0.f);
  float oy = fmaxf(ay * inv + bb.y, 0.f);
  ((float2*)out)[(size_t)nd * 64 + lane] = make_float2(ox, oy);
}

// ---------------- final linear + log_softmax ----------------

__global__ __launch_bounds__(64) void k_final(
    const float* __restrict__ h, const float* __restrict__ lw, const float* __restrict__ lb,
    float* __restrict__ out)
{
  const int nd = blockIdx.x;
  const int c = threadIdx.x;
  const float* hrow = h + (size_t)nd * 128;
  float acc = lb[c];
#pragma unroll 8
  for (int f = 0; f < 128; ++f) acc += hrow[f] * lw[f * 64 + c];
  float mx = acc;
#pragma unroll
  for (int off = 32; off > 0; off >>= 1) mx = fmaxf(mx, __shfl_xor(mx, off));
  float e = __expf(acc - mx);
  float ssum = e;
#pragma unroll
  for (int off = 32; off > 0; off >>= 1) ssum += __shfl_xor(ssum, off);
  out[(size_t)nd * 64 + c] = acc - mx - __logf(ssum);
}

// ---------------- launch ----------------

extern "C" void kernel_launch(void* const* d_in, const int* in_sizes, int n_in,
                              void* d_out, int out_size, void* d_ws, size_t ws_size,
                              hipStream_t stream) {
  const float* x   = (const float*)d_in[0];
  const int* ei    = (const int*)d_in[1];
  const int* etype = (const int*)d_in[2];
  const float* W1 = (const float*)d_in[3];
  const float* q1 = (const float*)d_in[4];
  const float* k1 = (const float*)d_in[5];
  const float* b1 = (const float*)d_in[6];
  const float* W2 = (const float*)d_in[7];
  const float* q2 = (const float*)d_in[8];
  const float* k2 = (const float*)d_in[9];
  const float* b2 = (const float*)d_in[10];
  const float* W3 = (const float*)d_in[11];
  const float* q3 = (const float*)d_in[12];
  const float* k3 = (const float*)d_in[13];
  const float* b3 = (const float*)d_in[14];
  const float* lw = (const float*)d_in[15];
  const float* lb = (const float*)d_in[16];
  float* outp = (float*)d_out;

  char* p = (char*)d_ws;
  auto alloc = [&](size_t bytes) {
    char* r = p;
    p += (bytes + 255) & ~(size_t)255;
    return r;
  };
  float* xr   = (float*)alloc((size_t)N_NODES * R_REL * H_DIM * 4);  // 204.8 MB
  float* qx   = (float*)alloc((size_t)N_NODES * R_REL * 4);
  float* kx   = (float*)alloc((size_t)N_NODES * R_REL * 4);
  float* hA   = (float*)alloc((size_t)N_NODES * H_DIM * 4);
  float* hB   = (float*)alloc((size_t)N_NODES * H_DIM * 4);
  int* rowptr = (int*)alloc((size_t)(N_NODES + 1) * 4);
  int* cursor = (int*)alloc((size_t)N_NODES * 4);
  int* hist   = (int*)alloc((size_t)N_NODES * 4);
  int* ssrc   = (int*)alloc((size_t)N_EDGES * 4);
  int* setype = (int*)alloc((size_t)N_EDGES * 4);
  __bf16* Whi = (__bf16*)alloc((size_t)3 * R_REL * 128 * 128 * 2);   // 786 KB
  __bf16* Wlo = (__bf16*)alloc((size_t)3 * R_REL * 128 * 128 * 2);

  const int* src = ei;            // edge_index[0]
  const int* dst = ei + N_EDGES;  // edge_index[1]

  // CSR build + W prep
  hipMemsetAsync(hist, 0, (size_t)N_NODES * 4, stream);
  k_hist<<<(N_EDGES + 255) / 256, 256, 0, stream>>>(dst, hist);
  k_prepw<<<(3 * R_REL * 128 * 128 + 255) / 256, 256, 0, stream>>>(W1, W2, W3, Whi, Wlo);
  k_scan<<<1, 1024, 0, stream>>>(hist, rowptr, cursor);
  k_scatter<<<(N_EDGES + 255) / 256, 256, 0, stream>>>(src, dst, etype, cursor, ssrc, setype);

  const int tgrid = (N_NODES + 63) / 64;
  const size_t WL = (size_t)R_REL * 128 * 128;

  // layer 1
  k_transform_mfma<<<tgrid, 256, 0, stream>>>(x, Whi, Wlo, q1, k1, xr, qx, kx);
  k_agg<<<N_NODES, 64, 0, stream>>>(xr, qx, kx, rowptr, ssrc, setype, b1, hA);
  // layer 2
  k_transform_mfma<<<tgrid, 256, 0, stream>>>(hA, Whi + WL, Wlo + WL, q2, k2, xr, qx, kx);
  k_agg<<<N_NODES, 64, 0, stream>>>(xr, qx, kx, rowptr, ssrc, setype, b2, hB);
  // layer 3
  k_transform_mfma<<<tgrid, 256, 0, stream>>>(hB, Whi + 2 * WL, Wlo + 2 * WL, q3, k3, xr, qx, kx);
  k_agg<<<N_NODES, 64, 0, stream>>>(xr, qx, kx, rowptr, ssrc, setype, b3, hA);
  // final linear + log_softmax
  k_final<<<N_NODES, 64, 0, stream>>>(hA, lw, lb, outp);
}